// Round 9
// baseline (154.449 us; speedup 1.0000x reference)
//
#include <hip/hip_runtime.h>

// ---------------- types ----------------
typedef __attribute__((ext_vector_type(8))) short bf16x8;   // 8 bf16 in 4 VGPRs
typedef __attribute__((ext_vector_type(4))) float f32x4;
typedef __attribute__((ext_vector_type(8))) unsigned short us8;

#define K_DIM 2048
#define QK_N  320     // 256 q cols + 64 k cols
#define SEQ   4096
#define BK    64
#define NCHUNK 32                      // K_DIM / BK
#define NHALF  160                     // N columns per block
#define BCHUNK 20480                   // bytes of one B chunk: 8 units * 160 cols * 16B
#define STRIP_BYTES 131072             // 32 rows * 2048 k * 2B = 64 t-steps * 2048B

__device__ __forceinline__ unsigned short f2bf(float f) {
    unsigned int u = __builtin_bit_cast(unsigned int, f);
    u += 0x7FFFu + ((u >> 16) & 1u);      // round-to-nearest-even
    return (unsigned short)(u >> 16);
}

// ---------------- W convert + re-layout ----------------
// ws layout: [2 N-halves][NCHUNK][8 k-units][160 cols][16B]
__global__ void cvt_w_swz(const float* __restrict__ Wq,
                          const float* __restrict__ Wk,
                          unsigned short* __restrict__ ws) {
    int id = blockIdx.x * 256 + threadIdx.x;   // 320*256 ids
    int c  = id >> 8;                          // 0..319 (output col)
    int k8 = id & 255;                         // 8-elem k group
    int k0 = k8 * 8;
    const float* src = (c < 256) ? (Wq + (size_t)c * K_DIM + k0)
                                 : (Wk + (size_t)(c - 256) * K_DIM + k0);
    float4 v0 = *reinterpret_cast<const float4*>(src);
    float4 v1 = *reinterpret_cast<const float4*>(src + 4);
    us8 o;
    o[0] = f2bf(v0.x); o[1] = f2bf(v0.y); o[2] = f2bf(v0.z); o[3] = f2bf(v0.w);
    o[4] = f2bf(v1.x); o[5] = f2bf(v1.y); o[6] = f2bf(v1.z); o[7] = f2bf(v1.w);
    int half = (c >= NHALF) ? 1 : 0;
    int cc   = c - half * NHALF;
    int kc = k0 / BK;            // chunk index 0..31
    int u  = (k0 % BK) >> 3;     // k-unit within chunk (0..7)
    size_t byteoff = (size_t)half * (NCHUNK * (size_t)BCHUNK)
                   + (size_t)kc * BCHUNK + ((size_t)(u * NHALF + cc) * 16);
    *reinterpret_cast<us8*>((char*)ws + byteoff) = o;
}

// ---------------- h convert + re-layout into MFMA fragment order ----------------
// h_swz layout: [256 strips][64 t-steps][2 rg][64 lanes][16B]  (one strip = 32
// rows of h). Per t-step a wave's 64 lanes read 1 KB CONTIGUOUS, advancing
// monotonically -> DRAM page-friendly streaming instead of 8KB-strided 128B
// touches. grid 1024: block = 8-row quarter of a strip; reads row-major.
__global__ __launch_bounds__(256) void cvt_h_swz(
    const float* __restrict__ h, char* __restrict__ hs) {
    const int strip = blockIdx.x >> 2;
    const int q     = blockIdx.x & 3;          // 8-row quarter
    char* sbase = hs + (size_t)strip * STRIP_BYTES;
#pragma unroll
    for (int i = 0; i < 8; ++i) {
        int row = q * 8 + i;                   // row within strip 0..31
        int k8  = threadIdx.x;                 // 8-float k group 0..255
        const float* src = h + (size_t)(strip * 32 + row) * K_DIM + k8 * 8;
        float4 v0 = *reinterpret_cast<const float4*>(src);
        float4 v1 = *reinterpret_cast<const float4*>(src + 4);
        us8 o;
        o[0] = f2bf(v0.x); o[1] = f2bf(v0.y); o[2] = f2bf(v0.z); o[3] = f2bf(v0.w);
        o[4] = f2bf(v1.x); o[5] = f2bf(v1.y); o[6] = f2bf(v1.z); o[7] = f2bf(v1.w);
        int t  = k8 >> 2;                      // t-step 0..63
        int lg = k8 & 3;                       // k-unit within t-step
        int rg = row >> 4;                     // wave row-group 0..1
        int lr = row & 15;
        size_t off = (size_t)t * 2048 + (size_t)rg * 1024
                   + (size_t)(lg * 16 + lr) * 16;
        *reinterpret_cast<us8*>(sbase + off) = o;
    }
}

// ---------------- projection GEMM: QKb[8192][320] = h * W^T (bf16 out) -------
// grid (2 N-halves, 256 M-strips) = 512 blocks x 256 threads (4 waves:
// 2 rg x 2 cg). block tile 32x160 over K=2048. No LDS, no barriers.
// A-frags: ONE contiguous 1KB-per-wave dwordx4 per t-step from h_swz (streams
// linearly). B-frags: L2-resident pre-swizzled W. 1-deep register ping-pong.
__global__ __launch_bounds__(256, 2) void proj_gemm(
    const char* __restrict__ Hs,            // h_swz (bf16 frag order)
    const unsigned short* __restrict__ Wsz, // re-laid-out W
    unsigned short* __restrict__ C)         // [8192][320] bf16
{
    const int tid  = threadIdx.x;
    const int lane = tid & 63;
    const int wid  = tid >> 6;          // 0..3
    const int rg   = wid >> 1;          // 0..1 (M row-group)
    const int cg   = wid & 1;           // 0..1 (N col-group)
    const int half = blockIdx.x;
    const int row0 = blockIdx.y * 32 + rg * 16;
    const int lr = lane & 15, lg = lane >> 4;

    // A: contiguous per-wave fragment stream
    const char* ahp = Hs + (size_t)blockIdx.y * STRIP_BYTES
                    + (size_t)rg * 1024 + (size_t)lane * 16;
    const char* wbase = (const char*)Wsz + (size_t)half * (NCHUNK * (size_t)BCHUNK)
                      + ((cg * 80 + lr) << 4);

    f32x4 acc[5];
#pragma unroll
    for (int j = 0; j < 5; ++j) acc[j] = (f32x4)0.f;

#define LOADB(t, b0, b1, b2, b3, b4) do {                                   \
        const char* bu = wbase + (size_t)((t) >> 1) * BCHUNK                \
                       + (size_t)((((t) & 1) * 4 + lg) * NHALF) * 16;       \
        b0 = *reinterpret_cast<const bf16x8*>(bu);                          \
        b1 = *reinterpret_cast<const bf16x8*>(bu + 256);                    \
        b2 = *reinterpret_cast<const bf16x8*>(bu + 512);                    \
        b3 = *reinterpret_cast<const bf16x8*>(bu + 768);                    \
        b4 = *reinterpret_cast<const bf16x8*>(bu + 1024);                   \
    } while (0)
#define LOADA(t, a) do {                                                    \
        a = *reinterpret_cast<const bf16x8*>(ahp + (size_t)(t) * 2048);     \
    } while (0)
#define COMPUTE(a, b0, b1, b2, b3, b4) do {                                 \
        acc[0] = __builtin_amdgcn_mfma_f32_16x16x32_bf16(a, b0, acc[0], 0, 0, 0); \
        acc[1] = __builtin_amdgcn_mfma_f32_16x16x32_bf16(a, b1, acc[1], 0, 0, 0); \
        acc[2] = __builtin_amdgcn_mfma_f32_16x16x32_bf16(a, b2, acc[2], 0, 0, 0); \
        acc[3] = __builtin_amdgcn_mfma_f32_16x16x32_bf16(a, b3, acc[3], 0, 0, 0); \
        acc[4] = __builtin_amdgcn_mfma_f32_16x16x32_bf16(a, b4, acc[4], 0, 0, 0); \
    } while (0)

    // ping-pong register sets (static names — rule #20)
    bf16x8 cb0, cb1, cb2, cb3, cb4, ca;
    bf16x8 nb0, nb1, nb2, nb3, nb4, na;

    LOADB(0, cb0, cb1, cb2, cb3, cb4);
    LOADA(0, ca);

    for (int t = 0; t < 64; t += 2) {
        // issue t+1 loads, then compute t
        LOADB(t + 1, nb0, nb1, nb2, nb3, nb4);
        LOADA(t + 1, na);
        COMPUTE(ca, cb0, cb1, cb2, cb3, cb4);
        // issue t+2 loads (clamped), then compute t+1
        const int t2 = (t + 2 < 64) ? t + 2 : 63;
        LOADB(t2, cb0, cb1, cb2, cb3, cb4);
        LOADA(t2, ca);
        COMPUTE(na, nb0, nb1, nb2, nb3, nb4);
    }
#undef LOADB
#undef LOADA
#undef COMPUTE

    // epilogue: C layout col=lane&15, row=(lane>>4)*4+r
    const int crow = row0 + lg * 4;
    const int ccol = half * NHALF + cg * 80 + lr;
#pragma unroll
    for (int j = 0; j < 5; ++j)
#pragma unroll
        for (int r = 0; r < 4; ++r)
            C[(size_t)(crow + r) * QK_N + ccol + j * 16] = f2bf(acc[j][r]);
}

// ---------------- scores: I[b,t,s] = sum_h w[h]*relu(Q_h K^T) ----------------
// grid (32,32,2); block 256 = 4 waves (2x2). block tile 128x128, wave tile 64x64.
// MFMA operands swapped (a=K-frag, b=Q-frag) so each lane's 4 acc regs are 4
// consecutive s values -> float4 stores.
__global__ __launch_bounds__(256) void scores_kernel(
    const unsigned short* __restrict__ QK,   // [B][4096][320] bf16
    const float* __restrict__ w,             // [4]
    float* __restrict__ out)                 // [B][4096][4096] fp32
{
    const int lane = threadIdx.x & 63;
    const int wid  = threadIdx.x >> 6;
    const int b  = blockIdx.z;
    const int t0 = blockIdx.y * 128 + (wid >> 1) * 64;
    const int s0 = blockIdx.x * 128 + (wid & 1) * 64;

    const int lr = lane & 15;
    const int lk = (lane >> 4) * 8;
    const int lg = lane >> 4;

    const unsigned short* Qb = QK + (size_t)b * SEQ * QK_N;
    const unsigned short* Kb = Qb + 256;

    float wv[4] = { w[0], w[1], w[2], w[3] };

    f32x4 fin[4][4];
#pragma unroll
    for (int i = 0; i < 4; ++i)
#pragma unroll
        for (int j = 0; j < 4; ++j) fin[i][j] = (f32x4)0.f;

    const unsigned short* qp = Qb + (size_t)(t0 + lr) * QK_N + lk;
    const unsigned short* kp = Kb + (size_t)(s0 + lr) * QK_N + lk;

#pragma unroll
    for (int h = 0; h < 4; ++h) {
        f32x4 acc[4][4];
#pragma unroll
        for (int i = 0; i < 4; ++i)
#pragma unroll
            for (int j = 0; j < 4; ++j) acc[i][j] = (f32x4)0.f;

#pragma unroll
        for (int ks = 0; ks < 2; ++ks) {
            bf16x8 qf[4], kf[4];
#pragma unroll
            for (int i = 0; i < 4; ++i)
                qf[i] = *reinterpret_cast<const bf16x8*>(
                    qp + (size_t)i * 16 * QK_N + h * 64 + ks * 32);
#pragma unroll
            for (int j = 0; j < 4; ++j)
                kf[j] = *reinterpret_cast<const bf16x8*>(
                    kp + (size_t)j * 16 * QK_N + ks * 32);
            // swapped: a=K (s in reg dim), b=Q (t on lane&15)
#pragma unroll
            for (int i = 0; i < 4; ++i)
#pragma unroll
                for (int j = 0; j < 4; ++j)
                    acc[i][j] = __builtin_amdgcn_mfma_f32_16x16x32_bf16(kf[j], qf[i], acc[i][j], 0, 0, 0);
        }
#pragma unroll
        for (int i = 0; i < 4; ++i)
#pragma unroll
            for (int j = 0; j < 4; ++j)
#pragma unroll
                for (int r = 0; r < 4; ++r)
                    fin[i][j][r] += wv[h] * fmaxf(acc[i][j][r], 0.f);
    }

    // store: lane holds t = t0+i*16+lr, s = s0+j*16+lg*4 .. +3 (contiguous)
    float* ob = out + (size_t)b * SEQ * SEQ;
#pragma unroll
    for (int i = 0; i < 4; ++i) {
        const size_t rbase = (size_t)(t0 + i * 16 + lr) * SEQ + s0 + lg * 4;
#pragma unroll
        for (int j = 0; j < 4; ++j) {
            float4 v;
            v.x = fin[i][j][0]; v.y = fin[i][j][1];
            v.z = fin[i][j][2]; v.w = fin[i][j][3];
            *reinterpret_cast<float4*>(&ob[rbase + j * 16]) = v;
        }
    }
}

// ---------------- launch ----------------
extern "C" void kernel_launch(void* const* d_in, const int* in_sizes, int n_in,
                              void* d_out, int out_size, void* d_ws, size_t ws_size,
                              hipStream_t stream) {
    const float* h  = (const float*)d_in[0];   // [2,4096,2048]
    const float* Wq = (const float*)d_in[1];   // [256,2048]
    const float* Wk = (const float*)d_in[2];   // [64,2048]
    const float* w  = (const float*)d_in[3];   // [4]
    float* out = (float*)d_out;                // [2,4096,4096]

    char* ws = (char*)d_ws;
    unsigned short* W_swz = (unsigned short*)ws;                       // 1.25 MB
    ws += 2 * (size_t)NCHUNK * BCHUNK;
    char* H_swz = ws;                                                  // 32 MB
    ws += (size_t)256 * STRIP_BYTES;
    unsigned short* QKb = (unsigned short*)ws;                         // 5 MB bf16

    cvt_w_swz<<<320, 256, 0, stream>>>(Wq, Wk, W_swz);
    cvt_h_swz<<<1024, 256, 0, stream>>>(h, H_swz);
    proj_gemm<<<dim3(2, 256), 256, 0, stream>>>(H_swz, W_swz, QKb);
    scores_kernel<<<dim3(32, 32, 2), 256, 0, stream>>>(QKb, w, out);
}